// Round 9
// baseline (443.057 us; speedup 1.0000x reference)
//
#include <hip/hip_runtime.h>
#include <hip/hip_bf16.h>

#define NN 16
#define CC 256
#define TT 64
#define VV 25
#define ICC 64
#define TV 1600      // TT*VV
#define CTV 409600   // CC*TV
#define NICTV 1638400  // elements per f-slice: 16*1600*64

typedef __bf16 v8bf __attribute__((ext_vector_type(8)));
typedef __bf16 v4bf __attribute__((ext_vector_type(4)));
typedef float f32x16 __attribute__((ext_vector_type(16)));

struct ConvPairs {
  const __bf16* wA[5];
  const __bf16* wB[5];
  const float*  bA[5];
  const float*  bB[5];
};

// ---------- x transpose to channels-last bf16: xt[n][p][c] = x[n][c][p]
__global__ __launch_bounds__(256) void xt_k(const float* __restrict__ x,
                                            __bf16* __restrict__ xt){
  __shared__ float tile[64][65];
  int p0 = blockIdx.x*64, c0 = blockIdx.y*64, n = blockIdx.z;
  int tid = threadIdx.x;
  for (int i = tid; i < 4096; i += 256){
    int cc = i >> 6, pp = i & 63;
    tile[cc][pp] = x[(size_t)n*CTV + (size_t)(c0+cc)*TV + p0 + pp];
  }
  __syncthreads();
  for (int i = tid; i < 4096; i += 256){
    int pp = i >> 6, cc = i & 63;
    xt[((size_t)n*TV + p0+pp)*256 + c0+cc] = (__bf16)tile[cc][pp];
  }
}

// ---------- conv9 weights, coalesced transpose: in [r=s*64+o][c][k] f32 -> out[r][k][c] bf16
// grid (192 r, 4 tensor), block 256
__global__ __launch_bounds__(256) void wcvt9t_k(const float* __restrict__ i0,
    const float* __restrict__ i1, const float* __restrict__ i2,
    const float* __restrict__ i3, __bf16* __restrict__ out){
  __shared__ float sm[2304];
  int r = blockIdx.x, t = blockIdx.y;
  const float* in = (t==0)?i0:(t==1)?i1:(t==2)?i2:i3;
  int tid = threadIdx.x;
  for (int i = tid; i < 2304; i += 256) sm[i] = in[(size_t)r*2304 + i];
  __syncthreads();
  __bf16* ob = out + (size_t)t*442368 + (size_t)r*2304;
  for (int i = tid; i < 2304; i += 256){
    int k = i >> 8, c = i & 255;
    ob[i] = (__bf16)sm[c*9 + k];
  }
}

// ---------- center-tap compact: wST [s*64+o][256][9] f32 -> [s][o][256] bf16 (tap 4)
__global__ void wcvtc_k(const float* __restrict__ w1, const float* __restrict__ w2,
                        __bf16* __restrict__ o1, __bf16* __restrict__ o2){
  int i = blockIdx.x*256 + threadIdx.x;
  if (i >= 49152) return;
  o1[i] = (__bf16)w1[i*9 + 4];
  o2[i] = (__bf16)w2[i*9 + 4];
}

// ---------- wa+wb -> bf16 (contiguous out)
__global__ void wcvtab_k(const float* __restrict__ wa, const float* __restrict__ wb,
                         __bf16* __restrict__ out){
  int i = blockIdx.x*256 + threadIdx.x;
  if (i >= 2*49152) return;
  out[i] = (__bf16)((i < 49152) ? wa[i] : wb[i - 49152]);
}

__global__ void wcvt_k(const float* __restrict__ in, __bf16* __restrict__ out, int total){
  int i = blockIdx.x*256 + threadIdx.x;
  if (i < total) out[i] = (__bf16)in[i];
}

// ---------- static graph transform: A_all[s] = ch3 + softmax_col(ch4) + PA
__global__ void a_all_k(const float* __restrict__ A, const float* __restrict__ PA,
                        float* __restrict__ Aall){
  int t = threadIdx.x;
  if (t >= 75) return;
  int s = t / 25, w = t % 25;
  float a[25], m[25];
  float mx = -3.4e38f;
  for (int v = 0; v < 25; ++v){
    float av = A[(s*25 + v)*25 + w];
    a[v] = av;
    float d = (v == w) ? 1.f : 0.f;
    float mm = (8.f*av*av*av*av - 4.f*av*av - 4.f*av + d) * 0.04f;
    m[v] = mm;
    mx = fmaxf(mx, mm);
  }
  float sum = 0.f;
  for (int v = 0; v < 25; ++v){ float e = __expf(m[v]-mx); m[v] = e; sum += e; }
  float inv = 1.f/sum;
  for (int v = 0; v < 25; ++v){
    float av = a[v];
    float d = (v == w) ? 1.f : 0.f;
    Aall[(s*25+v)*25 + w] = m[v]*inv + 4.f*av*av - av - 2.f*d + PA[(s*25+v)*25+w];
  }
}

// ---------- MFMA conv v4: WG = 4 waves (2 which x 2 ph), wave = 64o x 64p
// p-tile 128. Output channels-last: fbuf[slice][n][p][ic]
template<int NTAPS, int CW, int WSTRIDE>
__global__ __launch_bounds__(256, 3) void conv4_k(const __bf16* __restrict__ xt,
    ConvPairs cp, __bf16* __restrict__ fbuf){
  extern __shared__ __bf16 sm[];
  constexpr int HALO  = (NTAPS==9) ? 100 : 0;
  constexpr int NROWS = 128 + 2*HALO;
  constexpr int GPR   = CW/8;
  constexpr int NCH   = 256/CW;
  constexpr int KS    = CW/16;
  constexpr int NSTEP = NTAPS*KS;
  int p0 = blockIdx.x*128;
  int n  = blockIdx.y;
  int pr = blockIdx.z;
  int tid = threadIdx.x;
  int lane = tid & 63;
  int wave = tid >> 6;
  int which = wave >> 1, ph = wave & 1;
  int h = lane >> 5, l31 = lane & 31;
  const __bf16* wgt = which ? cp.wB[pr] : cp.wA[pr];
  const float* bias = which ? cp.bB[pr] : cp.bA[pr];
  const __bf16* xtn = xt + (size_t)n*CTV;
  const __bf16* wl = wgt + (size_t)l31*WSTRIDE + h*8;

  f32x16 acc[2][2];   // [oq][pq]
  #pragma unroll
  for (int a=0;a<2;++a)
    #pragma unroll
    for (int b=0;b<2;++b)
      #pragma unroll
      for (int r=0;r<16;++r) acc[a][b][r] = 0.f;

  int rowbase = ph*64 + l31;

  for (int ch=0; ch<NCH; ++ch){
    for (int s2 = tid; s2 < NROWS*GPR; s2 += 256){
      int row = s2 / GPR, g = s2 % GPR;
      int pg = p0 - HALO + row;
      uint4 val = make_uint4(0u,0u,0u,0u);
      if ((unsigned)pg < 1600u)
        val = *(const uint4*)(xtn + (size_t)pg*256 + ch*CW + g*8);
      int gs = (g + row) & (GPR-1);
      *(uint4*)(sm + row*CW + gs*8) = val;
    }
    __syncthreads();
    const __bf16* wc = wl + ch*CW;
    auto ldA = [&](int s, v8bf& A0, v8bf& A1){
      int tap = s / KS, ks = s % KS;
      const __bf16* p = wc + (size_t)tap*256 + ks*16;
      A0 = *(const v8bf*)(p);
      A1 = *(const v8bf*)(p + (size_t)32*WSTRIDE);
    };
    v8bf a0[2], a1[2];
    ldA(0, a0[0], a1[0]);
    if (NSTEP > 1) ldA(1, a0[1], a1[1]);
    #pragma unroll
    for (int s=0; s<NSTEP; ++s){
      int tap = s / KS, ks = s % KS;
      int rowb = (NTAPS==9 ? tap*25 : 0) + rowbase;
      v8bf b[2];
      #pragma unroll
      for (int pq=0; pq<2; ++pq){
        int row = rowb + pq*32;
        int gs = ((ks*2 + h) + row) & (GPR-1);
        b[pq] = *(const v8bf*)(sm + row*CW + gs*8);
      }
      int cur = s & 1;
      v8bf A0 = a0[cur], A1 = a1[cur];
      if (s+2 < NSTEP) ldA(s+2, a0[cur], a1[cur]);
      #pragma unroll
      for (int pq=0; pq<2; ++pq){
        acc[0][pq] = __builtin_amdgcn_mfma_f32_32x32x16_bf16(A0, b[pq], acc[0][pq], 0,0,0);
        acc[1][pq] = __builtin_amdgcn_mfma_f32_32x32x16_bf16(A1, b[pq], acc[1][pq], 0,0,0);
      }
    }
    __syncthreads();
  }

  // store channels-last: fbuf[slice][(n*TV+p)*64 + og], D col=l31 -> p
  __bf16* outb = fbuf + (size_t)(pr*2 + which)*NICTV + (size_t)n*TV*64;
  #pragma unroll
  for (int pq=0; pq<2; ++pq){
    int p = p0 + ph*64 + pq*32 + l31;
    if (p >= 1600) continue;
    __bf16* orow = outb + (size_t)p*64;
    #pragma unroll
    for (int oq=0; oq<2; ++oq){
      #pragma unroll
      for (int g=0; g<4; ++g){
        int og = oq*32 + 8*g + 4*h;
        v4bf pk;
        #pragma unroll
        for (int j=0;j<4;++j) pk[j] = (__bf16)(acc[oq][pq][4*g+j] + bias[og+j]);
        *(v4bf*)(orow + og) = pk;
      }
    }
  }
}

// ---------- u GEMM v3: ubuf[br][n][p][o] = sum_c wd[br][o][c]*xt[n][p][c]
// grid (25 ptile64, 16 n, 3 br), block 256 (4 waves = 4 o-slices of 64)
__global__ __launch_bounds__(256, 3) void ugemm3_k(const __bf16* __restrict__ xt,
    const __bf16* __restrict__ wdb, __bf16* __restrict__ ubuf){
  extern __shared__ __bf16 sm[];
  int p0 = blockIdx.x*64;
  int n  = blockIdx.y;
  int br = blockIdx.z;
  int tid = threadIdx.x;
  int lane = tid & 63;
  int os = tid >> 6;
  int h = lane >> 5, l31 = lane & 31;
  const __bf16* xtn = xt + (size_t)n*CTV;

  f32x16 acc[2][2];
  #pragma unroll
  for (int a=0;a<2;++a)
    #pragma unroll
    for (int b=0;b<2;++b)
      #pragma unroll
      for (int r=0;r<16;++r) acc[a][b][r] = 0.f;

  for (int s2 = tid; s2 < 64*32; s2 += 256){
    int row = s2 >> 5, g = s2 & 31;
    uint4 val = *(const uint4*)(xtn + (size_t)(p0+row)*256 + g*8);
    int gs = (g + row) & 31;
    *(uint4*)(sm + row*256 + gs*8) = val;
  }
  __syncthreads();

  const __bf16* wl = wdb + ((size_t)br*256 + os*64 + l31)*256 + h*8;
  auto ldA = [&](int ks, v8bf& A0, v8bf& A1){
    A0 = *(const v8bf*)(wl + ks*16);
    A1 = *(const v8bf*)(wl + (size_t)32*256 + ks*16);
  };
  v8bf a0[2], a1[2];
  ldA(0, a0[0], a1[0]);
  ldA(1, a0[1], a1[1]);
  #pragma unroll
  for (int ks=0; ks<16; ++ks){
    v8bf b[2];
    #pragma unroll
    for (int pq=0; pq<2; ++pq){
      int row = pq*32 + l31;
      int gs = ((ks*2 + h) + row) & 31;
      b[pq] = *(const v8bf*)(sm + row*256 + gs*8);
    }
    int cur = ks & 1;
    v8bf A0 = a0[cur], A1 = a1[cur];
    if (ks+2 < 16) ldA(ks+2, a0[cur], a1[cur]);
    #pragma unroll
    for (int pq=0; pq<2; ++pq){
      acc[0][pq] = __builtin_amdgcn_mfma_f32_32x32x16_bf16(A0, b[pq], acc[0][pq], 0,0,0);
      acc[1][pq] = __builtin_amdgcn_mfma_f32_32x32x16_bf16(A1, b[pq], acc[1][pq], 0,0,0);
    }
  }

  #pragma unroll
  for (int pq=0; pq<2; ++pq){
    int p = p0 + pq*32 + l31;
    __bf16* out = ubuf + ((size_t)(br*NN + n)*TV + p)*256;
    #pragma unroll
    for (int oq=0; oq<2; ++oq){
      #pragma unroll
      for (int g=0; g<4; ++g){
        int og = os*64 + oq*32 + 8*g + 4*h;
        v4bf pk;
        #pragma unroll
        for (int j=0;j<4;++j) pk[j] = (__bf16)acc[oq][pq][4*g+j];
        *(v4bf*)(out + og) = pk;
      }
    }
  }
}

// ---------- scores via MFMA: S[v][w] = sum_{k=(t,o)} F1[n][t*25+v][o]*F2[n][t*25+w][o]
// grid (4, 16 n, P pairs), block 256; wave = one k-chunk (4 t x 64 o = 256 k)
// part[tile][row*32+col] raw D tiles, tile = ((pairbase+pr)*16+n)*16+chunk
__global__ __launch_bounds__(256) void scores_m_k(const __bf16* __restrict__ fbuf,
                                                  float* __restrict__ part, int pairbase){
  int n = blockIdx.y, pr = blockIdx.z;
  int tid = threadIdx.x;
  int lane = tid & 63;
  int wave = tid >> 6;
  int chunk = blockIdx.x*4 + wave;
  int h = lane >> 5, l31 = lane & 31;
  const __bf16* f1 = fbuf + (size_t)(pr*2)*NICTV   + (size_t)n*TV*64;
  const __bf16* f2 = fbuf + (size_t)(pr*2+1)*NICTV + (size_t)n*TV*64;
  int t0 = chunk*4;

  f32x16 acc;
  #pragma unroll
  for (int r=0;r<16;++r) acc[r] = 0.f;

  auto off = [&](int s)->size_t{
    int t = t0 + (s>>2), og = s&3;
    return ((size_t)(t*25 + l31))*64 + og*16 + h*8;
  };
  v8bf A[2], B[2];
  { size_t o0 = off(0); A[0] = *(const v8bf*)(f1+o0); B[0] = *(const v8bf*)(f2+o0); }
  { size_t o1 = off(1); A[1] = *(const v8bf*)(f1+o1); B[1] = *(const v8bf*)(f2+o1); }
  #pragma unroll
  for (int s=0; s<16; ++s){
    int cur = s & 1;
    v8bf Ac = A[cur], Bc = B[cur];
    if (s+2 < 16){
      size_t o2 = off(s+2);
      A[cur] = *(const v8bf*)(f1+o2);
      B[cur] = *(const v8bf*)(f2+o2);
    }
    acc = __builtin_amdgcn_mfma_f32_32x32x16_bf16(Ac, Bc, acc, 0,0,0);
  }

  size_t tile = (((size_t)(pairbase+pr)*NN + n)*16 + chunk);
  float* pt = part + tile*1024;
  #pragma unroll
  for (int r=0; r<16; ++r){
    int row = (r&3) + 8*(r>>2) + 4*h;
    pt[row*32 + l31] = acc[r];
  }
}

// ---------- reduce all 9 pairs: softmax each, sum into branches, Ai3 = Aall + sums
// grid (16 n, 25 w), block 64 (lane = v)
__global__ __launch_bounds__(64) void reduce_all_k(const float* __restrict__ part,
    const float* __restrict__ Aall, float* __restrict__ Ai3){
  const int pairbr[9] = {0,1,2,0,2, 0,1,2,1};
  int n = blockIdx.x, w = blockIdx.y;
  int lane = threadIdx.x;
  float accbr[3] = {0.f, 0.f, 0.f};
  for (int pr=0; pr<9; ++pr){
    float s = 0.f;
    if (lane < 25){
      const float* pp = part + (((size_t)pr*NN + n)*16)*1024 + lane*32 + w;
      #pragma unroll
      for (int ch=0; ch<16; ++ch) s += pp[(size_t)ch*1024];
    }
    s *= (1.f/4096.f);
    float mval = (lane<25) ? s : -3.4e38f;
    #pragma unroll
    for (int d=32; d>0; d>>=1) mval = fmaxf(mval, __shfl_xor(mval, d));
    float e = (lane<25) ? __expf(s - mval) : 0.f;
    float sum = e;
    #pragma unroll
    for (int d=32; d>0; d>>=1) sum += __shfl_xor(sum, d);
    accbr[pairbr[pr]] += e / sum;
  }
  if (lane < 25){
    #pragma unroll
    for (int br=0; br<3; ++br)
      Ai3[((size_t)br*NN + n)*625 + lane*25 + w] =
        Aall[br*625 + lane*25 + w] + accbr[br];
  }
}

// ---------- epilogue: y + BN + residual + relu (float4 LDS reads)
__global__ __launch_bounds__(256) void yep_k(const float* __restrict__ x,
    const float* __restrict__ Ai3, const __bf16* __restrict__ ubuf,
    const float* __restrict__ bd, const float* __restrict__ gamma,
    const float* __restrict__ beta, const float* __restrict__ bnm,
    const float* __restrict__ bnv, float* __restrict__ out){
  __shared__ float ais[3][25*28];
  int t = blockIdx.x, n = blockIdx.y, o = threadIdx.x;
  for (int l=o; l<2100; l+=256){
    int br = l/700, r = l%700;
    int v = r/28, w = r%28;
    ais[br][v*28+w] = (w<25) ? Ai3[((size_t)br*NN + n)*625 + v*25 + w] : 0.f;
  }
  __syncthreads();
  float y[28];
  #pragma unroll
  for (int w=0;w<28;++w) y[w]=0.f;
  for (int br=0; br<3; ++br){
    const __bf16* up = ubuf + ((size_t)(br*NN + n)*TV + t*25)*256 + o;
    float uv[25];
    #pragma unroll
    for (int v=0;v<25;++v) uv[v] = (float)up[(size_t)v*256];
    y[0] += bd[br*256 + o];
    const float* ab = ais[br];
    for (int v=0; v<25; ++v){
      float u = uv[v];
      #pragma unroll
      for (int j=0; j<7; ++j){
        float4 a4 = *(const float4*)(ab + v*28 + 4*j);
        y[4*j+0] = fmaf(u, a4.x, y[4*j+0]);
        y[4*j+1] = fmaf(u, a4.y, y[4*j+1]);
        y[4*j+2] = fmaf(u, a4.z, y[4*j+2]);
        y[4*j+3] = fmaf(u, a4.w, y[4*j+3]);
      }
    }
  }
  // bias was only added into y[0]; add for remaining w
  float bsum = bd[o] + bd[256+o] + bd[512+o];
  float sc = gamma[o] * rsqrtf(bnv[o] + 1e-5f);
  float m  = bnm[o], be = beta[o];
  const float* xr = x + (size_t)n*CTV + (size_t)o*TV + t*25;
  float* orow = out + (size_t)n*CTV + (size_t)o*TV + t*25;
  // fix: y[0] already has bsum (accumulated per br); others need +bsum
  #pragma unroll
  for (int w=0; w<25; ++w){
    float yv = y[w] + ((w==0) ? 0.f : bsum);
    orow[w] = fmaxf((yv - m)*sc + be + xr[w], 0.f);
  }
}

extern "C" void kernel_launch(void* const* d_in, const int* in_sizes, int n_in,
                              void* d_out, int out_size, void* d_ws, size_t ws_size,
                              hipStream_t stream) {
  const float* x     = (const float*)d_in[0];
  const float* A     = (const float*)d_in[1];
  const float* PA    = (const float*)d_in[2];
  const float* wa    = (const float*)d_in[3];
  const float* ba    = (const float*)d_in[4];
  const float* wb    = (const float*)d_in[5];
  const float* bb    = (const float*)d_in[6];
  const float* wT1   = (const float*)d_in[7];
  const float* bT1   = (const float*)d_in[8];
  const float* wT2   = (const float*)d_in[9];
  const float* bT2   = (const float*)d_in[10];
  const float* wST11 = (const float*)d_in[11];
  const float* bST11 = (const float*)d_in[12];
  const float* wST12 = (const float*)d_in[13];
  const float* bST12 = (const float*)d_in[14];
  const float* wd    = (const float*)d_in[15];
  const float* bd    = (const float*)d_in[16];
  const float* gamma = (const float*)d_in[17];
  const float* beta  = (const float*)d_in[18];
  const float* bnm   = (const float*)d_in[19];
  const float* bnv   = (const float*)d_in[20];

  char* W = (char*)d_ws;
  float*  Aall = (float*)W;  W += 8192;
  float*  Ai3  = (float*)W;  W += 122880;    // 3*16*625 f32 (padded)
  __bf16* wab  = (__bf16*)W; W += 98304;     // 3*64*256 bf16
  __bf16* wbb  = (__bf16*)W; W += 98304;
  __bf16* wT1b = (__bf16*)W; W += 884736;    // 3*64*9*256 bf16 x4 contiguous
  __bf16* wT2b = (__bf16*)W; W += 884736;
  __bf16* wS1b = (__bf16*)W; W += 884736;
  __bf16* wS2b = (__bf16*)W; W += 884736;
  __bf16* wS1c = (__bf16*)W; W += 98304;     // center-tap compact [3][64][256]
  __bf16* wS2c = (__bf16*)W; W += 98304;
  __bf16* wdb  = (__bf16*)W; W += 393216;    // 3*256*256 bf16
  __bf16* xt   = (__bf16*)W; W += 13107200;  // 16*1600*256 bf16
  char* R = W;               W += 39321600;  // fbuf (10 slices, 32.8MB) / ubuf (39.3MB)
  float*  part = (float*)W;  W += 9437184;   // 9*16*16*1024 f32
  __bf16* fbuf = (__bf16*)R;
  __bf16* ubuf = (__bf16*)R;

  // prep
  xt_k<<<dim3(25,4,16), 256, 0, stream>>>(x, xt);
  wcvt9t_k<<<dim3(192,4), 256, 0, stream>>>(wT1, wT2, wST11, wST12, wT1b);
  wcvtc_k<<<192, 256, 0, stream>>>(wST11, wST12, wS1c, wS2c);
  wcvtab_k<<<(2*49152+255)/256, 256, 0, stream>>>(wa, wb, wab);
  wcvt_k<<<768, 256, 0, stream>>>(wd, wdb, 196608);
  a_all_k<<<1, 128, 0, stream>>>(A, PA, Aall);

  // phase 1: all "1x1" pairs (A x3, ST-even x2 via compact center-tap) -> pairs 0..4
  {
    ConvPairs cp;
    for (int i=0;i<3;++i){
      cp.wA[i] = wab + i*16384;  cp.wB[i] = wbb + i*16384;
      cp.bA[i] = ba + i*64;      cp.bB[i] = bb + i*64;
    }
    int evens[2] = {0, 2};
    for (int j=0;j<2;++j){
      int i = evens[j];
      cp.wA[3+j] = wS1c + i*16384;  cp.wB[3+j] = wS2c + i*16384;
      cp.bA[3+j] = bST11 + i*64;    cp.bB[3+j] = bST12 + i*64;
    }
    conv4_k<1,128,256><<<dim3(13,16,5), 256, 128*128*2, stream>>>(xt, cp, fbuf);
    scores_m_k<<<dim3(4,16,5), 256, 0, stream>>>(fbuf, part, 0);
  }

  // phase 2: all 9-tap pairs (T x3, ST-odd x1) -> pairs 5..8
  {
    ConvPairs cp;
    for (int i=0;i<3;++i){
      cp.wA[i] = wT1b + i*147456;  cp.wB[i] = wT2b + i*147456;
      cp.bA[i] = bT1 + i*64;       cp.bB[i] = bT2 + i*64;
    }
    cp.wA[3] = wS1b + 1*147456;  cp.wB[3] = wS2b + 1*147456;
    cp.bA[3] = bST11 + 1*64;     cp.bB[3] = bST12 + 1*64;
    cp.wA[4] = cp.wA[3]; cp.wB[4] = cp.wB[3]; cp.bA[4] = cp.bA[3]; cp.bB[4] = cp.bB[3];
    conv4_k<9,64,2304><<<dim3(13,16,4), 256, 328*64*2, stream>>>(xt, cp, fbuf);
    scores_m_k<<<dim3(4,16,4), 256, 0, stream>>>(fbuf, part, 5);
  }

  // u GEMM (overwrites fbuf region — fbuf dead after phase-2 scores)
  ugemm3_k<<<dim3(25,16,3), 256, 64*256*2, stream>>>(xt, wdb, ubuf);
  // all-pair softmax reduce -> Ai3
  reduce_all_k<<<dim3(16,25), 64, 0, stream>>>(part, Aall, Ai3);
  // epilogue
  yep_k<<<dim3(64,16), 256, 0, stream>>>(x, Ai3, ubuf, bd, gamma, beta, bnm, bnv,
                                         (float*)d_out);
}

// Round 10
// 372.094 us; speedup vs baseline: 1.1907x; 1.1907x over previous
//
#include <hip/hip_runtime.h>
#include <hip/hip_bf16.h>

#define NN 16
#define CC 256
#define TT 64
#define VV 25
#define ICC 64
#define TV 1600      // TT*VV
#define CTV 409600   // CC*TV
#define NICTV 1638400  // elements per f-slice: 16*1600*64

typedef __bf16 v8bf __attribute__((ext_vector_type(8)));
typedef __bf16 v4bf __attribute__((ext_vector_type(4)));
typedef float f32x16 __attribute__((ext_vector_type(16)));

struct ConvPairs {
  const __bf16* wA[5];
  const __bf16* wB[5];
  const float*  bA[5];
  const float*  bB[5];
};

// ---------- x transpose to channels-last bf16: xt[n][p][c] = x[n][c][p]
__global__ __launch_bounds__(256) void xt_k(const float* __restrict__ x,
                                            __bf16* __restrict__ xt){
  __shared__ float tile[64][65];
  int p0 = blockIdx.x*64, c0 = blockIdx.y*64, n = blockIdx.z;
  int tid = threadIdx.x;
  for (int i = tid; i < 4096; i += 256){
    int cc = i >> 6, pp = i & 63;
    tile[cc][pp] = x[(size_t)n*CTV + (size_t)(c0+cc)*TV + p0 + pp];
  }
  __syncthreads();
  for (int i = tid; i < 4096; i += 256){
    int pp = i >> 6, cc = i & 63;
    xt[((size_t)n*TV + p0+pp)*256 + c0+cc] = (__bf16)tile[cc][pp];
  }
}

// ---------- conv9 weights, coalesced transpose: in [r][c][k] f32 -> out [r][k][c] bf16
__global__ __launch_bounds__(256) void wcvt9t_k(const float* __restrict__ i0,
    const float* __restrict__ i1, const float* __restrict__ i2,
    const float* __restrict__ i3, __bf16* __restrict__ out){
  __shared__ float sm[2304];
  int r = blockIdx.x, t = blockIdx.y;
  const float* in = (t==0)?i0:(t==1)?i1:(t==2)?i2:i3;
  int tid = threadIdx.x;
  for (int i = tid; i < 2304; i += 256) sm[i] = in[(size_t)r*2304 + i];
  __syncthreads();
  __bf16* ob = out + (size_t)t*442368 + (size_t)r*2304;
  for (int i = tid; i < 2304; i += 256){
    int k = i >> 8, c = i & 255;
    ob[i] = (__bf16)sm[c*9 + k];
  }
}

// ---------- center-tap compact: wST [s*64+o][256][9] f32 -> [s][o][256] bf16 (tap 4)
__global__ void wcvtc_k(const float* __restrict__ w1, const float* __restrict__ w2,
                        __bf16* __restrict__ o1, __bf16* __restrict__ o2){
  int i = blockIdx.x*256 + threadIdx.x;
  if (i >= 49152) return;
  o1[i] = (__bf16)w1[i*9 + 4];
  o2[i] = (__bf16)w2[i*9 + 4];
}

// ---------- wa+wb -> bf16 (contiguous out)
__global__ void wcvtab_k(const float* __restrict__ wa, const float* __restrict__ wb,
                         __bf16* __restrict__ out){
  int i = blockIdx.x*256 + threadIdx.x;
  if (i >= 2*49152) return;
  out[i] = (__bf16)((i < 49152) ? wa[i] : wb[i - 49152]);
}

__global__ void wcvt_k(const float* __restrict__ in, __bf16* __restrict__ out, int total){
  int i = blockIdx.x*256 + threadIdx.x;
  if (i < total) out[i] = (__bf16)in[i];
}

// ---------- static graph transform: A_all[s] = ch3 + softmax_col(ch4) + PA
__global__ void a_all_k(const float* __restrict__ A, const float* __restrict__ PA,
                        float* __restrict__ Aall){
  int t = threadIdx.x;
  if (t >= 75) return;
  int s = t / 25, w = t % 25;
  float a[25], m[25];
  float mx = -3.4e38f;
  for (int v = 0; v < 25; ++v){
    float av = A[(s*25 + v)*25 + w];
    a[v] = av;
    float d = (v == w) ? 1.f : 0.f;
    float mm = (8.f*av*av*av*av - 4.f*av*av - 4.f*av + d) * 0.04f;
    m[v] = mm;
    mx = fmaxf(mx, mm);
  }
  float sum = 0.f;
  for (int v = 0; v < 25; ++v){ float e = __expf(m[v]-mx); m[v] = e; sum += e; }
  float inv = 1.f/sum;
  for (int v = 0; v < 25; ++v){
    float av = a[v];
    float d = (v == w) ? 1.f : 0.f;
    Aall[(s*25+v)*25 + w] = m[v]*inv + 4.f*av*av - av - 2.f*d + PA[(s*25+v)*25+w];
  }
}

// ---------- MFMA conv v5: wave = 64o x 128p (2 oq x 4 pq), depth-4 A-prefetch ring
// grid (7 ptile256, 16 n, NP pairs), block 256 (4 waves = 2 which x 2 ph)
// Output channels-last: fbuf[slice][n][p][ic]
template<int NTAPS, int CW, int WSTRIDE>
__global__ __launch_bounds__(256, 2) void conv5_k(const __bf16* __restrict__ xt,
    ConvPairs cp, __bf16* __restrict__ fbuf){
  extern __shared__ __bf16 sm[];
  constexpr int HALO  = (NTAPS==9) ? 100 : 0;
  constexpr int NROWS = 256 + 2*HALO;
  constexpr int GPR   = CW/8;
  constexpr int NCH   = 256/CW;
  constexpr int KS    = CW/16;
  constexpr int NSTEP = NTAPS*KS;
  int p0 = blockIdx.x*256;
  int n  = blockIdx.y;
  int pr = blockIdx.z;
  int tid = threadIdx.x;
  int lane = tid & 63;
  int wave = tid >> 6;
  int which = wave >> 1, ph = wave & 1;
  int h = lane >> 5, l31 = lane & 31;
  const __bf16* wgt = which ? cp.wB[pr] : cp.wA[pr];
  const float* bias = which ? cp.bB[pr] : cp.bA[pr];
  const __bf16* xtn = xt + (size_t)n*CTV;
  const __bf16* wl = wgt + (size_t)l31*WSTRIDE + h*8;

  f32x16 acc[2][4];   // [oq][pq]
  #pragma unroll
  for (int a=0;a<2;++a)
    #pragma unroll
    for (int b=0;b<4;++b)
      #pragma unroll
      for (int r=0;r<16;++r) acc[a][b][r] = 0.f;

  int rowbase = ph*128 + l31;

  for (int ch=0; ch<NCH; ++ch){
    for (int s2 = tid; s2 < NROWS*GPR; s2 += 256){
      int row = s2 / GPR, g = s2 % GPR;
      int pg = p0 - HALO + row;
      uint4 val = make_uint4(0u,0u,0u,0u);
      if ((unsigned)pg < 1600u)
        val = *(const uint4*)(xtn + (size_t)pg*256 + ch*CW + g*8);
      int gs = (g + row) & (GPR-1);
      *(uint4*)(sm + row*CW + gs*8) = val;
    }
    __syncthreads();
    const __bf16* wc = wl + ch*CW;
    auto ldA = [&](int s, v8bf& A0, v8bf& A1){
      int tap = s / KS, ks = s % KS;
      const __bf16* p = wc + (size_t)tap*256 + ks*16;
      A0 = *(const v8bf*)(p);
      A1 = *(const v8bf*)(p + (size_t)32*WSTRIDE);
    };
    v8bf a0[4], a1[4];
    ldA(0, a0[0], a1[0]);
    ldA(1, a0[1], a1[1]);
    ldA(2, a0[2], a1[2]);
    ldA(3, a0[3], a1[3]);
    #pragma unroll
    for (int s=0; s<NSTEP; ++s){
      int tap = s / KS, ks = s % KS;
      int rowb = (NTAPS==9 ? tap*25 : 0) + rowbase;
      v8bf b[4];
      #pragma unroll
      for (int pq=0; pq<4; ++pq){
        int row = rowb + pq*32;
        int gs = ((ks*2 + h) + row) & (GPR-1);
        b[pq] = *(const v8bf*)(sm + row*CW + gs*8);
      }
      int cur = s & 3;
      v8bf A0 = a0[cur], A1 = a1[cur];
      if (s+4 < NSTEP) ldA(s+4, a0[cur], a1[cur]);
      #pragma unroll
      for (int pq=0; pq<4; ++pq){
        acc[0][pq] = __builtin_amdgcn_mfma_f32_32x32x16_bf16(A0, b[pq], acc[0][pq], 0,0,0);
        acc[1][pq] = __builtin_amdgcn_mfma_f32_32x32x16_bf16(A1, b[pq], acc[1][pq], 0,0,0);
      }
    }
    __syncthreads();
  }

  // store channels-last: fbuf[slice][(n*TV+p)*64 + og]
  __bf16* outb = fbuf + (size_t)(pr*2 + which)*NICTV + (size_t)n*TV*64;
  #pragma unroll
  for (int pq=0; pq<4; ++pq){
    int p = p0 + ph*128 + pq*32 + l31;
    if (p >= 1600) continue;
    __bf16* orow = outb + (size_t)p*64;
    #pragma unroll
    for (int oq=0; oq<2; ++oq){
      #pragma unroll
      for (int g=0; g<4; ++g){
        int og = oq*32 + 8*g + 4*h;
        v4bf pk;
        #pragma unroll
        for (int j=0;j<4;++j) pk[j] = (__bf16)(acc[oq][pq][4*g+j] + bias[og+j]);
        *(v4bf*)(orow + og) = pk;
      }
    }
  }
}

// ---------- u GEMM: wave = 64o x 128p, depth-4 A ring; ubuf[br][n][p][o]
// grid (13 ptile128, 16 n, 3 br), block 256 (4 waves = o-slices of 64)
__global__ __launch_bounds__(256, 2) void ugemm4_k(const __bf16* __restrict__ xt,
    const __bf16* __restrict__ wdb, __bf16* __restrict__ ubuf){
  extern __shared__ __bf16 sm[];
  int p0 = blockIdx.x*128;
  int n  = blockIdx.y;
  int br = blockIdx.z;
  int tid = threadIdx.x;
  int lane = tid & 63;
  int os = tid >> 6;
  int h = lane >> 5, l31 = lane & 31;
  const __bf16* xtn = xt + (size_t)n*CTV;

  f32x16 acc[2][4];
  #pragma unroll
  for (int a=0;a<2;++a)
    #pragma unroll
    for (int b=0;b<4;++b)
      #pragma unroll
      for (int r=0;r<16;++r) acc[a][b][r] = 0.f;

  for (int s2 = tid; s2 < 128*32; s2 += 256){
    int row = s2 >> 5, g = s2 & 31;
    int pg = p0 + row;
    uint4 val = make_uint4(0u,0u,0u,0u);
    if (pg < 1600)
      val = *(const uint4*)(xtn + (size_t)pg*256 + g*8);
    int gs = (g + row) & 31;
    *(uint4*)(sm + row*256 + gs*8) = val;
  }
  __syncthreads();

  const __bf16* wl = wdb + ((size_t)br*256 + os*64 + l31)*256 + h*8;
  auto ldA = [&](int ks, v8bf& A0, v8bf& A1){
    A0 = *(const v8bf*)(wl + ks*16);
    A1 = *(const v8bf*)(wl + (size_t)32*256 + ks*16);
  };
  v8bf a0[4], a1[4];
  ldA(0, a0[0], a1[0]);
  ldA(1, a0[1], a1[1]);
  ldA(2, a0[2], a1[2]);
  ldA(3, a0[3], a1[3]);
  #pragma unroll
  for (int ks=0; ks<16; ++ks){
    v8bf b[4];
    #pragma unroll
    for (int pq=0; pq<4; ++pq){
      int row = pq*32 + l31;
      int gs = ((ks*2 + h) + row) & 31;
      b[pq] = *(const v8bf*)(sm + row*256 + gs*8);
    }
    int cur = ks & 3;
    v8bf A0 = a0[cur], A1 = a1[cur];
    if (ks+4 < 16) ldA(ks+4, a0[cur], a1[cur]);
    #pragma unroll
    for (int pq=0; pq<4; ++pq){
      acc[0][pq] = __builtin_amdgcn_mfma_f32_32x32x16_bf16(A0, b[pq], acc[0][pq], 0,0,0);
      acc[1][pq] = __builtin_amdgcn_mfma_f32_32x32x16_bf16(A1, b[pq], acc[1][pq], 0,0,0);
    }
  }

  #pragma unroll
  for (int pq=0; pq<4; ++pq){
    int p = p0 + pq*32 + l31;
    if (p >= 1600) continue;
    __bf16* out = ubuf + ((size_t)(br*NN + n)*TV + p)*256;
    #pragma unroll
    for (int oq=0; oq<2; ++oq){
      #pragma unroll
      for (int g=0; g<4; ++g){
        int og = os*64 + oq*32 + 8*g + 4*h;
        v4bf pk;
        #pragma unroll
        for (int j=0;j<4;++j) pk[j] = (__bf16)acc[oq][pq][4*g+j];
        *(v4bf*)(out + og) = pk;
      }
    }
  }
}

// ---------- scores via MFMA: S[v][w] = sum_{k=(t,o)} F1[n][t*25+v][o]*F2[n][t*25+w][o]
// grid (4, 16 n, P pairs), block 256; wave = one k-chunk (4 t x 64 o)
__global__ __launch_bounds__(256) void scores_m_k(const __bf16* __restrict__ fbuf,
                                                  float* __restrict__ part, int pairbase){
  int n = blockIdx.y, pr = blockIdx.z;
  int tid = threadIdx.x;
  int lane = tid & 63;
  int wave = tid >> 6;
  int chunk = blockIdx.x*4 + wave;
  int h = lane >> 5, l31 = lane & 31;
  const __bf16* f1 = fbuf + (size_t)(pr*2)*NICTV   + (size_t)n*TV*64;
  const __bf16* f2 = fbuf + (size_t)(pr*2+1)*NICTV + (size_t)n*TV*64;
  int t0 = chunk*4;

  f32x16 acc;
  #pragma unroll
  for (int r=0;r<16;++r) acc[r] = 0.f;

  auto off = [&](int s)->size_t{
    int t = t0 + (s>>2), og = s&3;
    return ((size_t)(t*25 + l31))*64 + og*16 + h*8;
  };
  v8bf A[2], B[2];
  { size_t o0 = off(0); A[0] = *(const v8bf*)(f1+o0); B[0] = *(const v8bf*)(f2+o0); }
  { size_t o1 = off(1); A[1] = *(const v8bf*)(f1+o1); B[1] = *(const v8bf*)(f2+o1); }
  #pragma unroll
  for (int s=0; s<16; ++s){
    int cur = s & 1;
    v8bf Ac = A[cur], Bc = B[cur];
    if (s+2 < 16){
      size_t o2 = off(s+2);
      A[cur] = *(const v8bf*)(f1+o2);
      B[cur] = *(const v8bf*)(f2+o2);
    }
    acc = __builtin_amdgcn_mfma_f32_32x32x16_bf16(Ac, Bc, acc, 0,0,0);
  }

  size_t tile = (((size_t)(pairbase+pr)*NN + n)*16 + chunk);
  float* pt = part + tile*1024;
  #pragma unroll
  for (int r=0; r<16; ++r){
    int row = (r&3) + 8*(r>>2) + 4*h;
    pt[row*32 + l31] = acc[r];
  }
}

// ---------- reduce all 9 pairs: softmax each, sum into branches, Ai3 = Aall + sums
__global__ __launch_bounds__(64) void reduce_all_k(const float* __restrict__ part,
    const float* __restrict__ Aall, float* __restrict__ Ai3){
  const int pairbr[9] = {0,1,2,0,2, 0,1,2,1};
  int n = blockIdx.x, w = blockIdx.y;
  int lane = threadIdx.x;
  float accbr[3] = {0.f, 0.f, 0.f};
  for (int pr=0; pr<9; ++pr){
    float s = 0.f;
    if (lane < 25){
      const float* pp = part + (((size_t)pr*NN + n)*16)*1024 + lane*32 + w;
      #pragma unroll
      for (int ch=0; ch<16; ++ch) s += pp[(size_t)ch*1024];
    }
    s *= (1.f/4096.f);
    float mval = (lane<25) ? s : -3.4e38f;
    #pragma unroll
    for (int d=32; d>0; d>>=1) mval = fmaxf(mval, __shfl_xor(mval, d));
    float e = (lane<25) ? __expf(s - mval) : 0.f;
    float sum = e;
    #pragma unroll
    for (int d=32; d>0; d>>=1) sum += __shfl_xor(sum, d);
    accbr[pairbr[pr]] += e / sum;
  }
  if (lane < 25){
    #pragma unroll
    for (int br=0; br<3; ++br)
      Ai3[((size_t)br*NN + n)*625 + lane*25 + w] =
        Aall[br*625 + lane*25 + w] + accbr[br];
  }
}

// ---------- epilogue: y + BN + residual + relu (float4 LDS reads)
__global__ __launch_bounds__(256) void yep_k(const float* __restrict__ x,
    const float* __restrict__ Ai3, const __bf16* __restrict__ ubuf,
    const float* __restrict__ bd, const float* __restrict__ gamma,
    const float* __restrict__ beta, const float* __restrict__ bnm,
    const float* __restrict__ bnv, float* __restrict__ out){
  __shared__ float ais[3][25*28];
  int t = blockIdx.x, n = blockIdx.y, o = threadIdx.x;
  for (int l=o; l<2100; l+=256){
    int br = l/700, r = l%700;
    int v = r/28, w = r%28;
    ais[br][v*28+w] = (w<25) ? Ai3[((size_t)br*NN + n)*625 + v*25 + w] : 0.f;
  }
  __syncthreads();
  float y[28];
  #pragma unroll
  for (int w=0;w<28;++w) y[w]=0.f;
  for (int br=0; br<3; ++br){
    const __bf16* up = ubuf + ((size_t)(br*NN + n)*TV + t*25)*256 + o;
    float uv[25];
    #pragma unroll
    for (int v=0;v<25;++v) uv[v] = (float)up[(size_t)v*256];
    const float* ab = ais[br];
    for (int v=0; v<25; ++v){
      float u = uv[v];
      #pragma unroll
      for (int j=0; j<7; ++j){
        float4 a4 = *(const float4*)(ab + v*28 + 4*j);
        y[4*j+0] = fmaf(u, a4.x, y[4*j+0]);
        y[4*j+1] = fmaf(u, a4.y, y[4*j+1]);
        y[4*j+2] = fmaf(u, a4.z, y[4*j+2]);
        y[4*j+3] = fmaf(u, a4.w, y[4*j+3]);
      }
    }
  }
  float bsum = bd[o] + bd[256+o] + bd[512+o];
  float sc = gamma[o] * rsqrtf(bnv[o] + 1e-5f);
  float m  = bnm[o], be = beta[o];
  const float* xr = x + (size_t)n*CTV + (size_t)o*TV + t*25;
  float* orow = out + (size_t)n*CTV + (size_t)o*TV + t*25;
  #pragma unroll
  for (int w=0; w<25; ++w)
    orow[w] = fmaxf((y[w] + bsum - m)*sc + be + xr[w], 0.f);
}

extern "C" void kernel_launch(void* const* d_in, const int* in_sizes, int n_in,
                              void* d_out, int out_size, void* d_ws, size_t ws_size,
                              hipStream_t stream) {
  const float* x     = (const float*)d_in[0];
  const float* A     = (const float*)d_in[1];
  const float* PA    = (const float*)d_in[2];
  const float* wa    = (const float*)d_in[3];
  const float* ba    = (const float*)d_in[4];
  const float* wb    = (const float*)d_in[5];
  const float* bb    = (const float*)d_in[6];
  const float* wT1   = (const float*)d_in[7];
  const float* bT1   = (const float*)d_in[8];
  const float* wT2   = (const float*)d_in[9];
  const float* bT2   = (const float*)d_in[10];
  const float* wST11 = (const float*)d_in[11];
  const float* bST11 = (const float*)d_in[12];
  const float* wST12 = (const float*)d_in[13];
  const float* bST12 = (const float*)d_in[14];
  const float* wd    = (const float*)d_in[15];
  const float* bd    = (const float*)d_in[16];
  const float* gamma = (const float*)d_in[17];
  const float* beta  = (const float*)d_in[18];
  const float* bnm   = (const float*)d_in[19];
  const float* bnv   = (const float*)d_in[20];

  char* W = (char*)d_ws;
  float*  Aall = (float*)W;  W += 8192;
  float*  Ai3  = (float*)W;  W += 122880;
  __bf16* wab  = (__bf16*)W; W += 98304;
  __bf16* wbb  = (__bf16*)W; W += 98304;
  __bf16* wT1b = (__bf16*)W; W += 884736;
  __bf16* wT2b = (__bf16*)W; W += 884736;
  __bf16* wS1b = (__bf16*)W; W += 884736;
  __bf16* wS2b = (__bf16*)W; W += 884736;
  __bf16* wS1c = (__bf16*)W; W += 98304;
  __bf16* wS2c = (__bf16*)W; W += 98304;
  __bf16* wdb  = (__bf16*)W; W += 393216;
  __bf16* xt   = (__bf16*)W; W += 13107200;
  char* R = W;               W += 39321600;  // fbuf (10 slices) / ubuf overlay
  float*  part = (float*)W;  W += 9437184;   // 9*16*16*1024 f32
  __bf16* fbuf = (__bf16*)R;
  __bf16* ubuf = (__bf16*)R;

  // prep
  xt_k<<<dim3(25,4,16), 256, 0, stream>>>(x, xt);
  wcvt9t_k<<<dim3(192,4), 256, 0, stream>>>(wT1, wT2, wST11, wST12, wT1b);
  wcvtc_k<<<192, 256, 0, stream>>>(wST11, wST12, wS1c, wS2c);
  wcvtab_k<<<(2*49152+255)/256, 256, 0, stream>>>(wa, wb, wab);
  wcvt_k<<<768, 256, 0, stream>>>(wd, wdb, 196608);
  a_all_k<<<1, 128, 0, stream>>>(A, PA, Aall);

  // phase 1: all "1x1" pairs (A x3, ST-even x2 via compact center-tap) -> pairs 0..4
  {
    ConvPairs cp;
    for (int i=0;i<3;++i){
      cp.wA[i] = wab + i*16384;  cp.wB[i] = wbb + i*16384;
      cp.bA[i] = ba + i*64;      cp.bB[i] = bb + i*64;
    }
    int evens[2] = {0, 2};
    for (int j=0;j<2;++j){
      int i = evens[j];
      cp.wA[3+j] = wS1c + i*16384;  cp.wB[3+j] = wS2c + i*16384;
      cp.bA[3+j] = bST11 + i*64;    cp.bB[3+j] = bST12 + i*64;
    }
    conv5_k<1,128,256><<<dim3(7,16,5), 256, 256*128*2, stream>>>(xt, cp, fbuf);
    scores_m_k<<<dim3(4,16,5), 256, 0, stream>>>(fbuf, part, 0);
  }

  // phase 2: all 9-tap pairs (T x3, ST-odd x1) -> pairs 5..8
  {
    ConvPairs cp;
    for (int i=0;i<3;++i){
      cp.wA[i] = wT1b + i*147456;  cp.wB[i] = wT2b + i*147456;
      cp.bA[i] = bT1 + i*64;       cp.bB[i] = bT2 + i*64;
    }
    cp.wA[3] = wS1b + 1*147456;  cp.wB[3] = wS2b + 1*147456;
    cp.bA[3] = bST11 + 1*64;     cp.bB[3] = bST12 + 1*64;
    cp.wA[4] = cp.wA[3]; cp.wB[4] = cp.wB[3]; cp.bA[4] = cp.bA[3]; cp.bB[4] = cp.bB[3];
    conv5_k<9,64,2304><<<dim3(7,16,4), 256, 456*64*2, stream>>>(xt, cp, fbuf);
    scores_m_k<<<dim3(4,16,4), 256, 0, stream>>>(fbuf, part, 5);
  }

  // u GEMM (overwrites fbuf region — dead after phase-2 scores)
  ugemm4_k<<<dim3(13,16,3), 256, 128*256*2, stream>>>(xt, wdb, ubuf);
  // all-pair softmax reduce -> Ai3
  reduce_all_k<<<dim3(16,25), 64, 0, stream>>>(part, Aall, Ai3);
  // epilogue
  yep_k<<<dim3(64,16), 256, 0, stream>>>(x, Ai3, ubuf, bd, gamma, beta, bnm, bnv,
                                         (float*)d_out);
}

// Round 11
// 362.049 us; speedup vs baseline: 1.2237x; 1.0277x over previous
//
#include <hip/hip_runtime.h>
#include <hip/hip_bf16.h>

#define NN 16
#define CC 256
#define TT 64
#define VV 25
#define ICC 64
#define TV 1600      // TT*VV
#define CTV 409600   // CC*TV
#define NICTV 1638400  // elements per f-slice: 16*1600*64

typedef __bf16 v8bf __attribute__((ext_vector_type(8)));
typedef __bf16 v4bf __attribute__((ext_vector_type(4)));
typedef float f32x16 __attribute__((ext_vector_type(16)));

struct ConvPairs {
  const __bf16* wA[5];
  const __bf16* wB[5];
  const float*  bA[5];
  const float*  bB[5];
};

// ---------- merged prep: sections by blockIdx.x
// [0,768)    wcvt9t: 4 conv9 weight tensors [r][c][k] f32 -> [t][r][k][c] bf16
// [768,960)  wcvtc : center-tap compact
// [960,1344) wcvtab: wa+wb -> bf16
// [1344,2112) wcvt : wd -> bf16
// [2112]     a_all
// [2113,3713) xt   : x -> channels-last bf16
__global__ __launch_bounds__(256) void prep_k(
    const float* __restrict__ x, __bf16* __restrict__ xt,
    const float* __restrict__ wT1, const float* __restrict__ wT2,
    const float* __restrict__ wST11, const float* __restrict__ wST12,
    __bf16* __restrict__ wT1b,
    __bf16* __restrict__ wS1c, __bf16* __restrict__ wS2c,
    const float* __restrict__ wa, const float* __restrict__ wb,
    __bf16* __restrict__ wab,
    const float* __restrict__ wd, __bf16* __restrict__ wdb,
    const float* __restrict__ A, const float* __restrict__ PA,
    float* __restrict__ Aall){
  __shared__ float smf[64*65];
  int b = blockIdx.x;
  int tid = threadIdx.x;
  if (b < 768){
    int r = b & 191, t = b >> 8;           // 192 r x 4 t  (768 = 192*4; b>>8 wrong) 
    r = b % 192; t = b / 192;
    const float* in = (t==0)?wT1:(t==1)?wT2:(t==2)?wST11:wST12;
    for (int i = tid; i < 2304; i += 256) smf[i] = in[(size_t)r*2304 + i];
    __syncthreads();
    __bf16* ob = wT1b + (size_t)t*442368 + (size_t)r*2304;
    for (int i = tid; i < 2304; i += 256){
      int k = i >> 8, c = i & 255;
      ob[i] = (__bf16)smf[c*9 + k];
    }
  } else if (b < 960){
    int i = (b-768)*256 + tid;
    if (i < 49152){
      wS1c[i] = (__bf16)wST11[i*9 + 4];
      wS2c[i] = (__bf16)wST12[i*9 + 4];
    }
  } else if (b < 1344){
    int i = (b-960)*256 + tid;
    if (i < 2*49152)
      wab[i] = (__bf16)((i < 49152) ? wa[i] : wb[i - 49152]);
  } else if (b < 2112){
    int i = (b-1344)*256 + tid;
    if (i < 196608) wdb[i] = (__bf16)wd[i];
  } else if (b == 2112){
    int t = tid;
    if (t < 75){
      int s = t / 25, w = t % 25;
      float a[25], m[25];
      float mx = -3.4e38f;
      for (int v = 0; v < 25; ++v){
        float av = A[(s*25 + v)*25 + w];
        a[v] = av;
        float d = (v == w) ? 1.f : 0.f;
        float mm = (8.f*av*av*av*av - 4.f*av*av - 4.f*av + d) * 0.04f;
        m[v] = mm;
        mx = fmaxf(mx, mm);
      }
      float sum = 0.f;
      for (int v = 0; v < 25; ++v){ float e = __expf(m[v]-mx); m[v] = e; sum += e; }
      float inv = 1.f/sum;
      for (int v = 0; v < 25; ++v){
        float av = a[v];
        float d = (v == w) ? 1.f : 0.f;
        Aall[(s*25+v)*25 + w] = m[v]*inv + 4.f*av*av - av - 2.f*d + PA[(s*25+v)*25+w];
      }
    }
  } else {
    int idx = b - 2113;
    int p0 = (idx % 25)*64, c0 = ((idx/25) & 3)*64, n = idx/100;
    for (int i = tid; i < 4096; i += 256){
      int cc = i >> 6, pp = i & 63;
      smf[cc*65+pp] = x[(size_t)n*CTV + (size_t)(c0+cc)*TV + p0 + pp];
    }
    __syncthreads();
    for (int i = tid; i < 4096; i += 256){
      int pp = i >> 6, cc = i & 63;
      xt[((size_t)n*TV + p0+pp)*256 + c0+cc] = (__bf16)smf[cc*65+pp];
    }
  }
}

// ---------- MFMA conv v6: wave = 64o x 128p, depth-4 A ring + depth-1 B prefetch
// grid (7 ptile256, 16 n, NP pairs), block 256 (4 waves = 2 which x 2 ph)
// Output channels-last: fbuf[slice][n][p][ic]
template<int NTAPS, int CW, int WSTRIDE>
__global__ __launch_bounds__(256, 2) void conv6_k(const __bf16* __restrict__ xt,
    ConvPairs cp, __bf16* __restrict__ fbuf){
  extern __shared__ __bf16 sm[];
  constexpr int HALO  = (NTAPS==9) ? 100 : 0;
  constexpr int NROWS = 256 + 2*HALO;
  constexpr int GPR   = CW/8;
  constexpr int NCH   = 256/CW;
  constexpr int KS    = CW/16;
  constexpr int NSTEP = NTAPS*KS;
  int p0 = blockIdx.x*256;
  int n  = blockIdx.y;
  int pr = blockIdx.z;
  int tid = threadIdx.x;
  int lane = tid & 63;
  int wave = tid >> 6;
  int which = wave >> 1, ph = wave & 1;
  int h = lane >> 5, l31 = lane & 31;
  const __bf16* wgt = which ? cp.wB[pr] : cp.wA[pr];
  const float* bias = which ? cp.bB[pr] : cp.bA[pr];
  const __bf16* xtn = xt + (size_t)n*CTV;
  const __bf16* wl = wgt + (size_t)l31*WSTRIDE + h*8;

  f32x16 acc[2][4];   // [oq][pq]
  #pragma unroll
  for (int a=0;a<2;++a)
    #pragma unroll
    for (int b=0;b<4;++b)
      #pragma unroll
      for (int r=0;r<16;++r) acc[a][b][r] = 0.f;

  int rowbase = ph*128 + l31;

  for (int ch=0; ch<NCH; ++ch){
    for (int s2 = tid; s2 < NROWS*GPR; s2 += 256){
      int row = s2 / GPR, g = s2 % GPR;
      int pg = p0 - HALO + row;
      uint4 val = make_uint4(0u,0u,0u,0u);
      if ((unsigned)pg < 1600u)
        val = *(const uint4*)(xtn + (size_t)pg*256 + ch*CW + g*8);
      int gs = (g + row) & (GPR-1);
      *(uint4*)(sm + row*CW + gs*8) = val;
    }
    __syncthreads();
    const __bf16* wc = wl + ch*CW;
    auto ldA = [&](int s, v8bf& A0, v8bf& A1){
      int tap = s / KS, ks = s % KS;
      const __bf16* p = wc + (size_t)tap*256 + ks*16;
      A0 = *(const v8bf*)(p);
      A1 = *(const v8bf*)(p + (size_t)32*WSTRIDE);
    };
    auto ldB = [&](int s, v8bf* bb){
      int tap = s / KS, ks = s % KS;
      int rowb = (NTAPS==9 ? tap*25 : 0) + rowbase;
      #pragma unroll
      for (int pq=0; pq<4; ++pq){
        int row = rowb + pq*32;
        int gs = ((ks*2 + h) + row) & (GPR-1);
        bb[pq] = *(const v8bf*)(sm + row*CW + gs*8);
      }
    };
    v8bf a0[4], a1[4];
    ldA(0, a0[0], a1[0]);
    ldA(1, a0[1], a1[1]);
    ldA(2, a0[2], a1[2]);
    ldA(3, a0[3], a1[3]);
    v8bf bc[4], bn[4];
    ldB(0, bc);
    #pragma unroll
    for (int s=0; s<NSTEP; ++s){
      if (s+1 < NSTEP) ldB(s+1, bn);
      int cur = s & 3;
      v8bf A0 = a0[cur], A1 = a1[cur];
      if (s+4 < NSTEP) ldA(s+4, a0[cur], a1[cur]);
      #pragma unroll
      for (int pq=0; pq<4; ++pq){
        acc[0][pq] = __builtin_amdgcn_mfma_f32_32x32x16_bf16(A0, bc[pq], acc[0][pq], 0,0,0);
        acc[1][pq] = __builtin_amdgcn_mfma_f32_32x32x16_bf16(A1, bc[pq], acc[1][pq], 0,0,0);
      }
      #pragma unroll
      for (int pq=0; pq<4; ++pq) bc[pq] = bn[pq];
    }
    __syncthreads();
  }

  __bf16* outb = fbuf + (size_t)(pr*2 + which)*NICTV + (size_t)n*TV*64;
  #pragma unroll
  for (int pq=0; pq<4; ++pq){
    int p = p0 + ph*128 + pq*32 + l31;
    if (p >= 1600) continue;
    __bf16* orow = outb + (size_t)p*64;
    #pragma unroll
    for (int oq=0; oq<2; ++oq){
      #pragma unroll
      for (int g=0; g<4; ++g){
        int og = oq*32 + 8*g + 4*h;
        v4bf pk;
        #pragma unroll
        for (int j=0;j<4;++j) pk[j] = (__bf16)(acc[oq][pq][4*g+j] + bias[og+j]);
        *(v4bf*)(orow + og) = pk;
      }
    }
  }
}

// ---------- u GEMM: wave = 64o x 128p, depth-4 A ring + depth-1 B prefetch
// grid (13 ptile128, 16 n, 3 br), block 256 (4 waves = o-slices of 64)
__global__ __launch_bounds__(256, 2) void ugemm5_k(const __bf16* __restrict__ xt,
    const __bf16* __restrict__ wdb, __bf16* __restrict__ ubuf){
  extern __shared__ __bf16 sm[];
  int p0 = blockIdx.x*128;
  int n  = blockIdx.y;
  int br = blockIdx.z;
  int tid = threadIdx.x;
  int lane = tid & 63;
  int os = tid >> 6;
  int h = lane >> 5, l31 = lane & 31;
  const __bf16* xtn = xt + (size_t)n*CTV;

  f32x16 acc[2][4];
  #pragma unroll
  for (int a=0;a<2;++a)
    #pragma unroll
    for (int b=0;b<4;++b)
      #pragma unroll
      for (int r=0;r<16;++r) acc[a][b][r] = 0.f;

  for (int s2 = tid; s2 < 128*32; s2 += 256){
    int row = s2 >> 5, g = s2 & 31;
    int pg = p0 + row;
    uint4 val = make_uint4(0u,0u,0u,0u);
    if (pg < 1600)
      val = *(const uint4*)(xtn + (size_t)pg*256 + g*8);
    int gs = (g + row) & 31;
    *(uint4*)(sm + row*256 + gs*8) = val;
  }
  __syncthreads();

  const __bf16* wl = wdb + ((size_t)br*256 + os*64 + l31)*256 + h*8;
  auto ldA = [&](int ks, v8bf& A0, v8bf& A1){
    A0 = *(const v8bf*)(wl + ks*16);
    A1 = *(const v8bf*)(wl + (size_t)32*256 + ks*16);
  };
  auto ldB = [&](int ks, v8bf* bb){
    #pragma unroll
    for (int pq=0; pq<4; ++pq){
      int row = pq*32 + l31;
      int gs = ((ks*2 + h) + row) & 31;
      bb[pq] = *(const v8bf*)(sm + row*256 + gs*8);
    }
  };
  v8bf a0[4], a1[4];
  ldA(0, a0[0], a1[0]);
  ldA(1, a0[1], a1[1]);
  ldA(2, a0[2], a1[2]);
  ldA(3, a0[3], a1[3]);
  v8bf bc[4], bn[4];
  ldB(0, bc);
  #pragma unroll
  for (int ks=0; ks<16; ++ks){
    if (ks+1 < 16) ldB(ks+1, bn);
    int cur = ks & 3;
    v8bf A0 = a0[cur], A1 = a1[cur];
    if (ks+4 < 16) ldA(ks+4, a0[cur], a1[cur]);
    #pragma unroll
    for (int pq=0; pq<4; ++pq){
      acc[0][pq] = __builtin_amdgcn_mfma_f32_32x32x16_bf16(A0, bc[pq], acc[0][pq], 0,0,0);
      acc[1][pq] = __builtin_amdgcn_mfma_f32_32x32x16_bf16(A1, bc[pq], acc[1][pq], 0,0,0);
    }
    #pragma unroll
    for (int pq=0; pq<4; ++pq) bc[pq] = bn[pq];
  }

  #pragma unroll
  for (int pq=0; pq<4; ++pq){
    int p = p0 + pq*32 + l31;
    if (p >= 1600) continue;
    __bf16* out = ubuf + ((size_t)(br*NN + n)*TV + p)*256;
    #pragma unroll
    for (int oq=0; oq<2; ++oq){
      #pragma unroll
      for (int g=0; g<4; ++g){
        int og = os*64 + oq*32 + 8*g + 4*h;
        v4bf pk;
        #pragma unroll
        for (int j=0;j<4;++j) pk[j] = (__bf16)acc[oq][pq][4*g+j];
        *(v4bf*)(out + og) = pk;
      }
    }
  }
}

// ---------- scores via MFMA: grid (4, 16 n, P pairs), block 256
__global__ __launch_bounds__(256) void scores_m_k(const __bf16* __restrict__ fbuf,
                                                  float* __restrict__ part, int pairbase){
  int n = blockIdx.y, pr = blockIdx.z;
  int tid = threadIdx.x;
  int lane = tid & 63;
  int wave = tid >> 6;
  int chunk = blockIdx.x*4 + wave;
  int h = lane >> 5, l31 = lane & 31;
  const __bf16* f1 = fbuf + (size_t)(pr*2)*NICTV   + (size_t)n*TV*64;
  const __bf16* f2 = fbuf + (size_t)(pr*2+1)*NICTV + (size_t)n*TV*64;
  int t0 = chunk*4;

  f32x16 acc;
  #pragma unroll
  for (int r=0;r<16;++r) acc[r] = 0.f;

  auto off = [&](int s)->size_t{
    int t = t0 + (s>>2), og = s&3;
    return ((size_t)(t*25 + l31))*64 + og*16 + h*8;
  };
  v8bf A[2], B[2];
  { size_t o0 = off(0); A[0] = *(const v8bf*)(f1+o0); B[0] = *(const v8bf*)(f2+o0); }
  { size_t o1 = off(1); A[1] = *(const v8bf*)(f1+o1); B[1] = *(const v8bf*)(f2+o1); }
  #pragma unroll
  for (int s=0; s<16; ++s){
    int cur = s & 1;
    v8bf Ac = A[cur], Bc = B[cur];
    if (s+2 < 16){
      size_t o2 = off(s+2);
      A[cur] = *(const v8bf*)(f1+o2);
      B[cur] = *(const v8bf*)(f2+o2);
    }
    acc = __builtin_amdgcn_mfma_f32_32x32x16_bf16(Ac, Bc, acc, 0,0,0);
  }

  size_t tile = (((size_t)(pairbase+pr)*NN + n)*16 + chunk);
  float* pt = part + tile*1024;
  #pragma unroll
  for (int r=0; r<16; ++r){
    int row = (r&3) + 8*(r>>2) + 4*h;
    pt[row*32 + l31] = acc[r];
  }
}

// ---------- reduce all 9 pairs -> Ai3
__global__ __launch_bounds__(64) void reduce_all_k(const float* __restrict__ part,
    const float* __restrict__ Aall, float* __restrict__ Ai3){
  const int pairbr[9] = {0,1,2,0,2, 0,1,2,1};
  int n = blockIdx.x, w = blockIdx.y;
  int lane = threadIdx.x;
  float accbr[3] = {0.f, 0.f, 0.f};
  for (int pr=0; pr<9; ++pr){
    float s = 0.f;
    if (lane < 25){
      const float* pp = part + (((size_t)pr*NN + n)*16)*1024 + lane*32 + w;
      #pragma unroll
      for (int ch=0; ch<16; ++ch) s += pp[(size_t)ch*1024];
    }
    s *= (1.f/4096.f);
    float mval = (lane<25) ? s : -3.4e38f;
    #pragma unroll
    for (int d=32; d>0; d>>=1) mval = fmaxf(mval, __shfl_xor(mval, d));
    float e = (lane<25) ? __expf(s - mval) : 0.f;
    float sum = e;
    #pragma unroll
    for (int d=32; d>0; d>>=1) sum += __shfl_xor(sum, d);
    accbr[pairbr[pr]] += e / sum;
  }
  if (lane < 25){
    #pragma unroll
    for (int br=0; br<3; ++br)
      Ai3[((size_t)br*NN + n)*625 + lane*25 + w] =
        Aall[br*625 + lane*25 + w] + accbr[br];
  }
}

// ---------- epilogue: y + BN + residual + relu
__global__ __launch_bounds__(256) void yep_k(const float* __restrict__ x,
    const float* __restrict__ Ai3, const __bf16* __restrict__ ubuf,
    const float* __restrict__ bd, const float* __restrict__ gamma,
    const float* __restrict__ beta, const float* __restrict__ bnm,
    const float* __restrict__ bnv, float* __restrict__ out){
  __shared__ float ais[3][25*28];
  int t = blockIdx.x, n = blockIdx.y, o = threadIdx.x;
  for (int l=o; l<2100; l+=256){
    int br = l/700, r = l%700;
    int v = r/28, w = r%28;
    ais[br][v*28+w] = (w<25) ? Ai3[((size_t)br*NN + n)*625 + v*25 + w] : 0.f;
  }
  __syncthreads();
  float y[28];
  #pragma unroll
  for (int w=0;w<28;++w) y[w]=0.f;
  for (int br=0; br<3; ++br){
    const __bf16* up = ubuf + ((size_t)(br*NN + n)*TV + t*25)*256 + o;
    float uv[25];
    #pragma unroll
    for (int v=0;v<25;++v) uv[v] = (float)up[(size_t)v*256];
    const float* ab = ais[br];
    for (int v=0; v<25; ++v){
      float u = uv[v];
      #pragma unroll
      for (int j=0; j<7; ++j){
        float4 a4 = *(const float4*)(ab + v*28 + 4*j);
        y[4*j+0] = fmaf(u, a4.x, y[4*j+0]);
        y[4*j+1] = fmaf(u, a4.y, y[4*j+1]);
        y[4*j+2] = fmaf(u, a4.z, y[4*j+2]);
        y[4*j+3] = fmaf(u, a4.w, y[4*j+3]);
      }
    }
  }
  float bsum = bd[o] + bd[256+o] + bd[512+o];
  float sc = gamma[o] * rsqrtf(bnv[o] + 1e-5f);
  float m  = bnm[o], be = beta[o];
  const float* xr = x + (size_t)n*CTV + (size_t)o*TV + t*25;
  float* orow = out + (size_t)n*CTV + (size_t)o*TV + t*25;
  #pragma unroll
  for (int w=0; w<25; ++w)
    orow[w] = fmaxf((y[w] + bsum - m)*sc + be + xr[w], 0.f);
}

extern "C" void kernel_launch(void* const* d_in, const int* in_sizes, int n_in,
                              void* d_out, int out_size, void* d_ws, size_t ws_size,
                              hipStream_t stream) {
  const float* x     = (const float*)d_in[0];
  const float* A     = (const float*)d_in[1];
  const float* PA    = (const float*)d_in[2];
  const float* wa    = (const float*)d_in[3];
  const float* ba    = (const float*)d_in[4];
  const float* wb    = (const float*)d_in[5];
  const float* bb    = (const float*)d_in[6];
  const float* wT1   = (const float*)d_in[7];
  const float* bT1   = (const float*)d_in[8];
  const float* wT2   = (const float*)d_in[9];
  const float* bT2   = (const float*)d_in[10];
  const float* wST11 = (const float*)d_in[11];
  const float* bST11 = (const float*)d_in[12];
  const float* wST12 = (const float*)d_in[13];
  const float* bST12 = (const float*)d_in[14];
  const float* wd    = (const float*)d_in[15];
  const float* bd    = (const float*)d_in[16];
  const float* gamma = (const float*)d_in[17];
  const float* beta  = (const float*)d_in[18];
  const float* bnm   = (const float*)d_in[19];
  const float* bnv   = (const float*)d_in[20];

  char* W = (char*)d_ws;
  float*  Aall = (float*)W;  W += 8192;
  float*  Ai3  = (float*)W;  W += 122880;
  __bf16* wab  = (__bf16*)W; W += 98304;     // wa bf16 (first half) + wb (second half)
  __bf16* wbb  = (__bf16*)W; W += 98304;
  __bf16* wT1b = (__bf16*)W; W += 884736;    // 4 tensors contiguous
  __bf16* wT2b = (__bf16*)W; W += 884736;
  __bf16* wS1b = (__bf16*)W; W += 884736;
  __bf16* wS2b = (__bf16*)W; W += 884736;
  __bf16* wS1c = (__bf16*)W; W += 98304;
  __bf16* wS2c = (__bf16*)W; W += 98304;
  __bf16* wdb  = (__bf16*)W; W += 393216;
  __bf16* xt   = (__bf16*)W; W += 13107200;
  char* R = W;               W += 39321600;  // fbuf (10 slices) / ubuf overlay
  float*  part = (float*)W;  W += 9437184;   // 9*16*16*1024 f32
  __bf16* fbuf = (__bf16*)R;
  __bf16* ubuf = (__bf16*)R;

  // merged prep (wab buffer holds wa then wb contiguously: wbb = wab + 49152)
  prep_k<<<3713, 256, 0, stream>>>(x, xt, wT1, wT2, wST11, wST12, wT1b,
                                   wS1c, wS2c, wa, wb, wab, wd, wdb, A, PA, Aall);

  // phase 1: all "1x1" pairs (A x3, ST-even x2 via compact center-tap) -> pairs 0..4
  {
    ConvPairs cp;
    for (int i=0;i<3;++i){
      cp.wA[i] = wab + i*16384;  cp.wB[i] = wbb + i*16384;
      cp.bA[i] = ba + i*64;      cp.bB[i] = bb + i*64;
    }
    int evens[2] = {0, 2};
    for (int j=0;j<2;++j){
      int i = evens[j];
      cp.wA[3+j] = wS1c + i*16384;  cp.wB[3+j] = wS2c + i*16384;
      cp.bA[3+j] = bST11 + i*64;    cp.bB[3+j] = bST12 + i*64;
    }
    conv6_k<1,128,256><<<dim3(7,16,5), 256, 256*128*2, stream>>>(xt, cp, fbuf);
    scores_m_k<<<dim3(4,16,5), 256, 0, stream>>>(fbuf, part, 0);
  }

  // phase 2: all 9-tap pairs (T x3, ST-odd x1) -> pairs 5..8
  {
    ConvPairs cp;
    for (int i=0;i<3;++i){
      cp.wA[i] = wT1b + i*147456;  cp.wB[i] = wT2b + i*147456;
      cp.bA[i] = bT1 + i*64;       cp.bB[i] = bT2 + i*64;
    }
    cp.wA[3] = wS1b + 1*147456;  cp.wB[3] = wS2b + 1*147456;
    cp.bA[3] = bST11 + 1*64;     cp.bB[3] = bST12 + 1*64;
    cp.wA[4] = cp.wA[3]; cp.wB[4] = cp.wB[3]; cp.bA[4] = cp.bA[3]; cp.bB[4] = cp.bB[3];
    conv6_k<9,64,2304><<<dim3(7,16,4), 256, 456*64*2, stream>>>(xt, cp, fbuf);
    scores_m_k<<<dim3(4,16,4), 256, 0, stream>>>(fbuf, part, 5);
  }

  // u GEMM (overwrites fbuf region — dead after phase-2 scores)
  ugemm5_k<<<dim3(13,16,3), 256, 128*256*2, stream>>>(xt, wdb, ubuf);
  // all-pair softmax reduce -> Ai3
  reduce_all_k<<<dim3(16,25), 64, 0, stream>>>(part, Aall, Ai3);
  // epilogue
  yep_k<<<dim3(64,16), 256, 0, stream>>>(x, Ai3, ubuf, bd, gamma, beta, bnm, bnv,
                                         (float*)d_out);
}